// Round 9
// baseline (6710.299 us; speedup 1.0000x reference)
//
#include <hip/hip_runtime.h>

typedef short s16;
typedef short bf16x8 __attribute__((ext_vector_type(8)));
typedef float f32x4 __attribute__((ext_vector_type(4)));

constexpr int kB = 1024, kT = 64, kD = 512, kH = 256;
constexpr int NSEG = 14;
// element counts per input (setup_inputs order) and exclusive prefix offsets
// z_init t  W1     b1  W2    b2  W3     b3  Wqkv   bqkv Wo     bo  gamma beta
// 524288 64 131072 256 65536 256 131072 512 786432 1536 262144 512 512   512
constexpr int kOff[NSEG] = {0, 524288, 524352, 655424, 655680, 721216, 721472,
                            852544, 853056, 1639488, 1641024, 1903168, 1903680, 1904192};
constexpr int kTotalConv = 1904704;

__device__ __forceinline__ float bs2f(s16 s) {
    return __uint_as_float(((unsigned)(unsigned short)s) << 16);
}
__device__ __forceinline__ s16 f2bs(float f) {
    unsigned u = __float_as_uint(f);
    unsigned r = (u + 0x7fffu + ((u >> 16) & 1u)) >> 16;
    return (s16)r;
}
__device__ __forceinline__ f32x4 mfma16(bf16x8 a, bf16x8 b, f32x4 c) {
    return __builtin_amdgcn_mfma_f32_16x16x32_bf16(a, b, c, 0, 0, 0);
}
__device__ __forceinline__ float gelu(float x) {
    return 0.5f * x * (1.0f + erff(x * 0.70710678118654752f));
}

// Forced async weight load: volatile asm cannot be sunk/rematerialized.
#define GLD(dst, ptr, OFF) \
    asm volatile("global_load_dwordx4 %0, %1, off offset:" #OFF : "=v"(dst) : "v"(ptr))
// Counted wait (T4): N loads may remain in flight. sched_barrier required
// (rule #18) so register-only MFMAs can't hoist above the wait.
#define VMWAIT(N) do { asm volatile("s_waitcnt vmcnt(" #N ")" ::: "memory"); \
                       __builtin_amdgcn_sched_barrier(0); } while (0)
// LDS-only barrier: drains lgkmcnt (ds_write visibility) but leaves global
// loads in flight across the barrier (unlike __syncthreads' vmcnt(0) drain).
#define LDSBAR do { asm volatile("s_waitcnt lgkmcnt(0)" ::: "memory"); \
                    __builtin_amdgcn_s_barrier(); \
                    asm volatile("" ::: "memory"); \
                    __builtin_amdgcn_sched_barrier(0); } while (0)

// ---------------------------------------------------------------------------
// dtype detect: t_steps[0..1] as one 32-bit word. bf16: [0, bf16(0.05)] ->
// 0x3D4D0000 != 0.  f32: first float 0.0f -> 0x00000000.
// flag = 1 means inputs are f32.
// ---------------------------------------------------------------------------
__global__ void detect_kernel(const unsigned* __restrict__ ts, int* __restrict__ flag) {
    if (threadIdx.x == 0 && blockIdx.x == 0) flag[0] = (ts[0] == 0u) ? 1 : 0;
}

struct ConvArgs { const void* src[NSEG]; };

__global__ __launch_bounds__(256) void convert_kernel(ConvArgs a, s16* __restrict__ dst,
                                                      const int* __restrict__ flag) {
    const int f = flag[0];
    for (int i = blockIdx.x * 256 + threadIdx.x; i < kTotalConv; i += gridDim.x * 256) {
        int s = 0;
        #pragma unroll
        for (int j = 1; j < NSEG; ++j) if (i >= kOff[j]) s = j;
        int local = i - kOff[s];
        s16 v;
        if (f) v = f2bs(((const float*)a.src[s])[local]);
        else   v = ((const s16*)a.src[s])[local];
        dst[i] = v;
    }
}

// ============================================================================
// ODE kernel: 64 blocks x 1024 threads (16 waves = 4/SIMD). Block owns 16
// rows of B. Wave w owns h-cols [w*16,w*16+16) for GEMM1/2 and out-cols
// [w*32,w*32+32) for GEMM3.
//   - asm-forced batched loads with COUNTED vmcnt (never 0 mid-phase):
//     f1a/f1b consumed at vmcnt(8)/(8); W2 issued under GEMM1 half B;
//     W3 in 4-frag slices consumed at vmcnt(12/8/4/0).
//   - raw s_barrier + lgkmcnt(0) (LDSBAR): W2/W3 loads stay in flight
//     across barriers (HIP __syncthreads would drain vmcnt(0)).
//   - 4 waves/SIMD double the latency-hiding pool vs the 8-wave variants.
//   - e==3 stage stores enter the vmcnt queue ahead of next eval's loads;
//     in-order vmcnt retirement keeps the counted waits correct:
//     [8 st|8 f1a|8 f1b] -> VMWAIT(8) retires stores+f1a exactly.
// Peak live ~126 VGPR <= the hard 128 cap of a 1024-thread block.
// ============================================================================
__global__ __launch_bounds__(1024) void ode_kernel(
    const s16* __restrict__ zin, const s16* __restrict__ ts,
    const s16* __restrict__ W1, const s16* __restrict__ b1,
    const s16* __restrict__ W2, const s16* __restrict__ b2,
    const s16* __restrict__ W3, const s16* __restrict__ b3,
    s16* __restrict__ stage)
{
    __shared__ __align__(16) s16 sArg[16 * 520];   // [16][520]
    __shared__ __align__(16) s16 sH1[16 * 264];    // [16][264]
    __shared__ __align__(16) s16 sH2[16 * 264];    // [16][264]
    __shared__ float sScale[16];

    const int tid = threadIdx.x;
    const int w = tid >> 6;          // wave 0..15
    const int lane = tid & 63;
    const int quad = lane >> 4;
    const int c = lane & 15;
    const int r0 = blockIdx.x * 16;

    const float dt  = bs2f(ts[1]) - bs2f(ts[0]);
    const float hdt = 0.5f * dt;
    const float dt6 = dt / 6.0f;

    // ---- per-row adaptive scale (wave w handles row w) ----
    {
        const s16* zrow = zin + (size_t)(r0 + w) * kD;
        float sum = 0.f, ssq = 0.f;
        for (int i = 0; i < 8; ++i) {
            float v = bs2f(zrow[lane + 64 * i]);
            sum += v; ssq += v * v;
        }
        for (int m = 1; m < 64; m <<= 1) {
            sum += __shfl_xor(sum, m, 64);
            ssq += __shfl_xor(ssq, m, 64);
        }
        float zn = sqrtf(ssq);
        float mean = sum / (float)kD;
        float var = (ssq - (float)kD * mean * mean) / (float)(kD - 1); // ddof=1
        float sc = zn / (var + 1e-6f);
        sc = fminf(fmaxf(sc, 0.8f), 1.2f);
        if (lane == 0) sScale[w] = sc;
    }
    __syncthreads();

    // ---- z registers: wave w owns cols [w*32, w*32+32) ----
    const int colbase = w * 32;
    float zreg[2][4], accR[2][4];
    #pragma unroll
    for (int nt = 0; nt < 2; ++nt)
        #pragma unroll
        for (int rr = 0; rr < 4; ++rr) {
            int m = quad * 4 + rr, col = colbase + nt * 16 + c;
            zreg[nt][rr] = bs2f(zin[(size_t)(r0 + m) * kD + col]) * sScale[m];
            accR[nt][rr] = 0.f;
        }
    // ---- initial arg = bf16(z0): wave w fills row w ----
    {
        const s16* zrow = zin + (size_t)(r0 + w) * kD;
        float sc = sScale[w];
        s16* dst = sArg + w * 520 + lane * 8;
        #pragma unroll
        for (int j = 0; j < 8; ++j) dst[j] = f2bs(bs2f(zrow[lane * 8 + j]) * sc);
    }
    const float b1v = bs2f(b1[w * 16 + c]);
    const float b2v = bs2f(b2[w * 16 + c]);
    float b3v[2];
    b3v[0] = bs2f(b3[colbase + c]);
    b3v[1] = bs2f(b3[colbase + 16 + c]);

    // per-lane weight base pointers (asm offsets are bytes, 13-bit signed)
    const s16* w1p  = W1 + (size_t)(w * 16 + c) * kD + quad * 8;
    const s16* w2p  = W2 + (size_t)(w * 16 + c) * kH + quad * 8;
    const s16* w3p0 = W3 + (size_t)(w * 32 + c) * kH + quad * 8;
    const s16* w3p1 = w3p0 + 16 * kH;

    __syncthreads();

    #pragma unroll 1
    for (int t = 0; t < kT; ++t) {
        #pragma unroll 1
        for (int e = 0; e < 4; ++e) {
            // ===== Phase 1: GEMM1 (K=512), one n-tile per wave =====
            bf16x8 f1a[8], f1b[8], f2w[8];
            GLD(f1a[0], w1p, 0);   GLD(f1a[1], w1p, 64);
            GLD(f1a[2], w1p, 128); GLD(f1a[3], w1p, 192);
            GLD(f1a[4], w1p, 256); GLD(f1a[5], w1p, 320);
            GLD(f1a[6], w1p, 384); GLD(f1a[7], w1p, 448);
            GLD(f1b[0], w1p, 512); GLD(f1b[1], w1p, 576);
            GLD(f1b[2], w1p, 640); GLD(f1b[3], w1p, 704);
            GLD(f1b[4], w1p, 768); GLD(f1b[5], w1p, 832);
            GLD(f1b[6], w1p, 896); GLD(f1b[7], w1p, 960);
            VMWAIT(8);   // f1a ready (f1b still flying; retires prior stores too)
            f32x4 a1 = {0.f, 0.f, 0.f, 0.f};
            #pragma unroll
            for (int kk = 0; kk < 8; ++kk) {
                bf16x8 av = *(const bf16x8*)(sArg + c * 520 + kk * 32 + quad * 8);
                a1 = mfma16(av, f1a[kk], a1);
            }
            // W2 batch issues under GEMM1's second half
            GLD(f2w[0], w2p, 0);   GLD(f2w[1], w2p, 64);
            GLD(f2w[2], w2p, 128); GLD(f2w[3], w2p, 192);
            GLD(f2w[4], w2p, 256); GLD(f2w[5], w2p, 320);
            GLD(f2w[6], w2p, 384); GLD(f2w[7], w2p, 448);
            VMWAIT(8);   // f1b ready (f2w flying)
            #pragma unroll
            for (int kk = 0; kk < 8; ++kk) {
                bf16x8 av = *(const bf16x8*)(sArg + c * 520 + (8 + kk) * 32 + quad * 8);
                a1 = mfma16(av, f1b[kk], a1);
            }
            #pragma unroll
            for (int rr = 0; rr < 4; ++rr)
                sH1[(quad * 4 + rr) * 264 + w * 16 + c] = f2bs(gelu(a1[rr] + b1v));
            LDSBAR;      // f2w stays in flight across the barrier

            // ===== Phase 2: GEMM2 (K=256) =====
            bf16x8 f3a[4], f3b[4], f3c[4], f3d[4];
            GLD(f3a[0], w3p0, 0);   GLD(f3a[1], w3p1, 0);
            GLD(f3a[2], w3p0, 64);  GLD(f3a[3], w3p1, 64);
            GLD(f3b[0], w3p0, 128); GLD(f3b[1], w3p1, 128);
            GLD(f3b[2], w3p0, 192); GLD(f3b[3], w3p1, 192);
            VMWAIT(8);   // f2w ready (f3a/f3b flying)
            f32x4 a2 = {0.f, 0.f, 0.f, 0.f};
            #pragma unroll
            for (int kk = 0; kk < 8; ++kk) {
                bf16x8 av = *(const bf16x8*)(sH1 + c * 264 + kk * 32 + quad * 8);
                a2 = mfma16(av, f2w[kk], a2);
            }
            GLD(f3c[0], w3p0, 256); GLD(f3c[1], w3p1, 256);
            GLD(f3c[2], w3p0, 320); GLD(f3c[3], w3p1, 320);
            GLD(f3d[0], w3p0, 384); GLD(f3d[1], w3p1, 384);
            GLD(f3d[2], w3p0, 448); GLD(f3d[3], w3p1, 448);
            #pragma unroll
            for (int rr = 0; rr < 4; ++rr)
                sH2[(quad * 4 + rr) * 264 + w * 16 + c] = f2bs(gelu(a2[rr] + b2v));
            LDSBAR;      // f3a..f3d stay in flight across the barrier

            // ===== Phase 3: GEMM3 (K=256), 2 n-tiles, staggered waits =====
            f32x4 a3[2];
            a3[0] = {0.f, 0.f, 0.f, 0.f};
            a3[1] = {0.f, 0.f, 0.f, 0.f};
            VMWAIT(12);  // f3a ready
            #pragma unroll
            for (int kk = 0; kk < 2; ++kk) {
                bf16x8 av = *(const bf16x8*)(sH2 + c * 264 + kk * 32 + quad * 8);
                a3[0] = mfma16(av, f3a[kk * 2 + 0], a3[0]);
                a3[1] = mfma16(av, f3a[kk * 2 + 1], a3[1]);
            }
            VMWAIT(8);   // f3b ready
            #pragma unroll
            for (int kk = 2; kk < 4; ++kk) {
                bf16x8 av = *(const bf16x8*)(sH2 + c * 264 + kk * 32 + quad * 8);
                a3[0] = mfma16(av, f3b[(kk - 2) * 2 + 0], a3[0]);
                a3[1] = mfma16(av, f3b[(kk - 2) * 2 + 1], a3[1]);
            }
            VMWAIT(4);   // f3c ready
            #pragma unroll
            for (int kk = 4; kk < 6; ++kk) {
                bf16x8 av = *(const bf16x8*)(sH2 + c * 264 + kk * 32 + quad * 8);
                a3[0] = mfma16(av, f3c[(kk - 4) * 2 + 0], a3[0]);
                a3[1] = mfma16(av, f3c[(kk - 4) * 2 + 1], a3[1]);
            }
            VMWAIT(0);   // f3d ready
            #pragma unroll
            for (int kk = 6; kk < 8; ++kk) {
                bf16x8 av = *(const bf16x8*)(sH2 + c * 264 + kk * 32 + quad * 8);
                a3[0] = mfma16(av, f3d[(kk - 6) * 2 + 0], a3[0]);
                a3[1] = mfma16(av, f3d[(kk - 6) * 2 + 1], a3[1]);
            }

            // ===== RK4 accumulate / advance =====
            const float wsum = (e == 0 || e == 3) ? 1.f : 2.f;
            const float cstep = (e == 2) ? dt : hdt;
            #pragma unroll
            for (int nt = 0; nt < 2; ++nt) {
                #pragma unroll
                for (int rr = 0; rr < 4; ++rr) {
                    float fv = a3[nt][rr] + b3v[nt];
                    accR[nt][rr] += wsum * fv;
                    int m = quad * 4 + rr;
                    int col = colbase + nt * 16 + c;
                    float argv;
                    if (e < 3) {
                        argv = zreg[nt][rr] + cstep * fv;
                    } else {
                        float zn2 = zreg[nt][rr] + dt6 * accR[nt][rr];
                        zn2 = (zn2 != zn2) ? 0.f : zn2;  // NaN guard
                        zreg[nt][rr] = zn2;
                        accR[nt][rr] = 0.f;
                        argv = zn2;
                        stage[(size_t)(r0 + m) * kT * kD + (size_t)t * kD + col] = f2bs(zn2);
                    }
                    sArg[m * 520 + col] = f2bs(argv);
                }
            }
            LDSBAR;
        }
    }
}

// ============================================================================
// Attention kernel: 1024 blocks (one per batch row) x 256 threads (4 waves).
// Reads z_stack from stage; writes z_final to outp (bf16 or f32 per flag).
// Static LDS 55.3 KB. P and ctx overlay the dead Q buffer.
// ============================================================================
__global__ __launch_bounds__(256) void attn_kernel(
    const s16* __restrict__ zin,
    const s16* __restrict__ Wqkv, const s16* __restrict__ bqkv,
    const s16* __restrict__ Wo, const s16* __restrict__ bo,
    const s16* __restrict__ gm, const s16* __restrict__ bt,
    const s16* __restrict__ stage, void* __restrict__ outp,
    const int* __restrict__ flag, int mode)
{
    __shared__ __align__(16) s16 sQ[64 * 136];   // Q -> P -> ctx (per-wave rows)
    __shared__ __align__(16) s16 sK[64 * 136];
    __shared__ __align__(16) s16 sVT[128 * 72];  // V transposed [d][t]
    __shared__ __align__(16) s16 sMean[512];
    __shared__ __align__(16) s16 sZi[512];
    float* psum = (float*)sQ;                    // preamble overlay: [4][512] f32 (8 KB < 17.4 KB)

    const int tid = threadIdx.x;
    const int w = tid >> 6, lane = tid & 63, quad = lane >> 4, c = lane & 15;
    const int b = blockIdx.x;
    const int f32out = mode ? flag[0] : 0;
    const s16* zs = stage + (size_t)b * kT * kD;   // this block's z_stack [64][512]

    // ---- preamble: z_init row; column means of z_stack over T ----
    for (int i = tid; i < kD; i += 256) sZi[i] = zin[(size_t)b * kD + i];
    {
        float s[8] = {0, 0, 0, 0, 0, 0, 0, 0};
        const int phase = tid >> 6, cg = (tid & 63) * 8;
        for (int i = 0; i < 16; ++i) {
            int t = phase + 4 * i;
            bf16x8 v = *(const bf16x8*)(zs + (size_t)t * kD + cg);
            #pragma unroll
            for (int j = 0; j < 8; ++j) s[j] += bs2f(v[j]);
        }
        #pragma unroll
        for (int j = 0; j < 8; ++j) psum[phase * kD + cg + j] = s[j];
    }
    __syncthreads();
    for (int col = tid; col < kD; col += 256) {
        float m = (psum[col] + psum[kD + col] + psum[2 * kD + col] + psum[3 * kD + col]) * (1.f / 64.f);
        sMean[col] = f2bs(m);
    }
    __syncthreads();

    // ---- A-fragments of z_dc for this wave's 16 rows (t = w*16 + c) ----
    bf16x8 afrag[16];
    #pragma unroll
    for (int kk = 0; kk < 16; ++kk) {
        int k0 = kk * 32 + quad * 8;
        bf16x8 zv = *(const bf16x8*)(zs + (size_t)(w * 16 + c) * kD + k0);
        bf16x8 o;
        #pragma unroll
        for (int j = 0; j < 8; ++j) {
            float zd = bs2f(zv[j]) - 0.05f * (bs2f(sMean[k0 + j]) - bs2f(sZi[k0 + j]));
            o[j] = f2bs(zd);
        }
        afrag[kk] = o;
    }

    f32x4 xacc[32];
    #pragma unroll
    for (int nt = 0; nt < 32; ++nt) xacc[nt] = {0.f, 0.f, 0.f, 0.f};

    const float iscl = 0.08838834764831845f;  // 1/sqrt(128)

    for (int h = 0; h < 4; ++h) {
        __syncthreads();  // protect sQ/sK/sVT rewrite vs prior head's readers
        // ---- qkv for head h: mat 0=Q, 1=K, 2=V ----
        for (int mat = 0; mat < 3; ++mat) {
            f32x4 acc[8];
            #pragma unroll
            for (int nt = 0; nt < 8; ++nt) acc[nt] = {0.f, 0.f, 0.f, 0.f};
            const s16* Wbase = Wqkv + (size_t)(mat * 512 + h * 128 + c) * kD + quad * 8;
            #pragma unroll
            for (int kk = 0; kk < 16; ++kk) {
                bf16x8 a = afrag[kk];
                #pragma unroll
                for (int nt = 0; nt < 8; ++nt) {
                    bf16x8 bb = *(const bf16x8*)(Wbase + (size_t)(nt * 16) * kD + kk * 32);
                    acc[nt] = mfma16(a, bb, acc[nt]);
                }
            }
            #pragma unroll
            for (int nt = 0; nt < 8; ++nt)
                #pragma unroll
                for (int rr = 0; rr < 4; ++rr) {
                    int n = h * 128 + nt * 16 + c;
                    float v = acc[nt][rr] + bs2f(bqkv[mat * 512 + n]);
                    int trow = w * 16 + quad * 4 + rr, dcol = nt * 16 + c;
                    if (mat == 0)      sQ[trow * 136 + dcol] = f2bs(v);
                    else if (mat == 1) sK[trow * 136 + dcol] = f2bs(v);
                    else               sVT[dcol * 72 + trow] = f2bs(v);
                }
        }
        __syncthreads();

        // ---- S = Q K^T (wave's 16 q-rows x 64 k-cols) ----
        f32x4 sfr[4];
        #pragma unroll
        for (int nt = 0; nt < 4; ++nt) sfr[nt] = {0.f, 0.f, 0.f, 0.f};
        #pragma unroll
        for (int kk = 0; kk < 4; ++kk) {
            bf16x8 a = *(const bf16x8*)(sQ + (w * 16 + c) * 136 + kk * 32 + quad * 8);
            #pragma unroll
            for (int nt = 0; nt < 4; ++nt) {
                bf16x8 bb = *(const bf16x8*)(sK + (nt * 16 + c) * 136 + kk * 32 + quad * 8);
                sfr[nt] = mfma16(a, bb, sfr[nt]);
            }
        }
        // ---- softmax along k (within quad: 16 lanes x 4 regs) ----
        #pragma unroll
        for (int rr = 0; rr < 4; ++rr) {
            float v[4];
            #pragma unroll
            for (int nt = 0; nt < 4; ++nt) v[nt] = sfr[nt][rr] * iscl;
            float mx = fmaxf(fmaxf(v[0], v[1]), fmaxf(v[2], v[3]));
            for (int m = 1; m < 16; m <<= 1) mx = fmaxf(mx, __shfl_xor(mx, m, 64));
            float sm = 0.f;
            #pragma unroll
            for (int nt = 0; nt < 4; ++nt) { v[nt] = __expf(v[nt] - mx); sm += v[nt]; }
            for (int m = 1; m < 16; m <<= 1) sm += __shfl_xor(sm, m, 64);
            float inv = 1.0f / sm;
            // P overlays dead Q (own rows only; no wave reads another wave's Q rows)
            #pragma unroll
            for (int nt = 0; nt < 4; ++nt)
                sQ[(w * 16 + quad * 4 + rr) * 136 + nt * 16 + c] = f2bs(v[nt] * inv);
        }
        // ---- ctx_h = P @ V  (K=64) ----
        f32x4 o[8];
        #pragma unroll
        for (int nt = 0; nt < 8; ++nt) o[nt] = {0.f, 0.f, 0.f, 0.f};
        #pragma unroll
        for (int kk = 0; kk < 2; ++kk) {
            bf16x8 a = *(const bf16x8*)(sQ + (w * 16 + c) * 136 + kk * 32 + quad * 8);
            #pragma unroll
            for (int nt = 0; nt < 8; ++nt) {
                bf16x8 bb = *(const bf16x8*)(sVT + (nt * 16 + c) * 72 + kk * 32 + quad * 8);
                o[nt] = mfma16(a, bb, o[nt]);
            }
        }
        // ctx_h -> sQ (own rows; P consumed)
        #pragma unroll
        for (int nt = 0; nt < 8; ++nt)
            #pragma unroll
            for (int rr = 0; rr < 4; ++rr)
                sQ[(w * 16 + quad * 4 + rr) * 136 + nt * 16 + c] = f2bs(o[nt][rr]);
        // ---- out-proj partial: x += ctx_h @ Wo[:, h*128:+128]^T ----
        #pragma unroll
        for (int kk = 0; kk < 4; ++kk) {
            bf16x8 a = *(const bf16x8*)(sQ + (w * 16 + c) * 136 + kk * 32 + quad * 8);
            #pragma unroll
            for (int nt = 0; nt < 32; ++nt) {
                bf16x8 bb = *(const bf16x8*)(Wo + (size_t)(nt * 16 + c) * kD + h * 128 + kk * 32 + quad * 8);
                xacc[nt] = mfma16(a, bb, xacc[nt]);
            }
        }
    }

    // ---- epilogue: x = z_dc + att_out + bo; LayerNorm; store ----
    float sum[4] = {0, 0, 0, 0}, ssq[4] = {0, 0, 0, 0};
    #pragma unroll
    for (int nt = 0; nt < 32; ++nt)
        #pragma unroll
        for (int rr = 0; rr < 4; ++rr) {
            int trow = w * 16 + quad * 4 + rr;
            int col = nt * 16 + c;
            float zd = bs2f(zs[(size_t)trow * kD + col]) - 0.05f * (bs2f(sMean[col]) - bs2f(sZi[col]));
            float x = xacc[nt][rr] + bs2f(bo[col]) + zd;
            xacc[nt][rr] = x;
            sum[rr] += x; ssq[rr] += x * x;
        }
    float mu[4], rstd[4];
    #pragma unroll
    for (int rr = 0; rr < 4; ++rr) {
        float s = sum[rr], q = ssq[rr];
        for (int m = 1; m < 16; m <<= 1) { s += __shfl_xor(s, m, 64); q += __shfl_xor(q, m, 64); }
        float mm = s / (float)kD;
        float var = q / (float)kD - mm * mm;   // biased, eps 1e-5
        mu[rr] = mm;
        rstd[rr] = rsqrtf(var + 1e-5f);
    }
    #pragma unroll
    for (int nt = 0; nt < 32; ++nt)
        #pragma unroll
        for (int rr = 0; rr < 4; ++rr) {
            int trow = w * 16 + quad * 4 + rr;
            int col = nt * 16 + c;
            float v = (xacc[nt][rr] - mu[rr]) * rstd[rr] * bs2f(gm[col]) + bs2f(bt[col]);
            v = (v != v) ? 0.f : v;
            size_t idx = ((size_t)b * kT + trow) * kD + col;
            if (f32out) ((float*)outp)[idx] = v;
            else        ((s16*)outp)[idx] = f2bs(v);
        }
}

extern "C" void kernel_launch(void* const* d_in, const int* in_sizes, int n_in,
                              void* d_out, int out_size, void* d_ws, size_t ws_size,
                              hipStream_t stream) {
    (void)in_sizes; (void)n_in; (void)out_size;
    const size_t kStageElems = (size_t)kB * kT * kD;
    const size_t kNeed = 16 + (size_t)kTotalConv * 2 + kStageElems * 2;   // ~70.9 MB

    const s16* p[NSEG];
    s16* stage;
    void* outp = d_out;
    const int* flag = nullptr;
    int mode = 0;

    if (ws_size >= kNeed) {
        int* flg = (int*)d_ws;
        s16* conv = (s16*)((char*)d_ws + 16);
        stage = (s16*)((char*)d_ws + 16 + (size_t)kTotalConv * 2);
        detect_kernel<<<dim3(1), dim3(64), 0, stream>>>((const unsigned*)d_in[1], flg);
        ConvArgs ca;
        for (int i = 0; i < NSEG; ++i) ca.src[i] = d_in[i];
        convert_kernel<<<dim3(512), dim3(256), 0, stream>>>(ca, conv, flg);
        for (int i = 0; i < NSEG; ++i) p[i] = conv + kOff[i];
        flag = flg;
        mode = 1;
    } else {
        for (int i = 0; i < NSEG; ++i) p[i] = (const s16*)d_in[i];
        stage = (s16*)d_out;   // in-place staging (bf16 assumed)
    }

    ode_kernel<<<dim3(64), dim3(1024), 0, stream>>>(
        p[0], p[1], p[2], p[3], p[4], p[5], p[6], p[7], stage);
    attn_kernel<<<dim3(kB), dim3(256), 0, stream>>>(
        p[0], p[8], p[9], p[10], p[11], p[12], p[13], stage, outp, flag, mode);
}

// Round 10
// 6683.418 us; speedup vs baseline: 1.0040x; 1.0040x over previous
//
#include <hip/hip_runtime.h>

typedef short s16;
typedef short bf16x8 __attribute__((ext_vector_type(8)));
typedef float f32x4 __attribute__((ext_vector_type(4)));

constexpr int kB = 1024, kT = 64, kD = 512, kH = 256;
constexpr int NSEG = 14;
// element counts per input (setup_inputs order) and exclusive prefix offsets
// z_init t  W1     b1  W2    b2  W3     b3  Wqkv   bqkv Wo     bo  gamma beta
// 524288 64 131072 256 65536 256 131072 512 786432 1536 262144 512 512   512
constexpr int kOff[NSEG] = {0, 524288, 524352, 655424, 655680, 721216, 721472,
                            852544, 853056, 1639488, 1641024, 1903168, 1903680, 1904192};
constexpr int kTotalConv = 1904704;

__device__ __forceinline__ float bs2f(s16 s) {
    return __uint_as_float(((unsigned)(unsigned short)s) << 16);
}
__device__ __forceinline__ s16 f2bs(float f) {
    unsigned u = __float_as_uint(f);
    unsigned r = (u + 0x7fffu + ((u >> 16) & 1u)) >> 16;
    return (s16)r;
}
__device__ __forceinline__ f32x4 mfma16(bf16x8 a, bf16x8 b, f32x4 c) {
    return __builtin_amdgcn_mfma_f32_16x16x32_bf16(a, b, c, 0, 0, 0);
}
__device__ __forceinline__ float gelu(float x) {
    return 0.5f * x * (1.0f + erff(x * 0.70710678118654752f));
}

// Forced async weight load: volatile asm cannot be sunk/rematerialized.
#define GLD(dst, ptr, OFF) \
    asm volatile("global_load_dwordx4 %0, %1, off offset:" #OFF : "=v"(dst) : "v"(ptr))
// Counted wait (T4): N loads may remain in flight. sched_barrier required
// (rule #18) so register-only MFMAs can't hoist above the wait.
#define VMWAIT(N) do { asm volatile("s_waitcnt vmcnt(" #N ")" ::: "memory"); \
                       __builtin_amdgcn_sched_barrier(0); } while (0)
// LDS-only barrier: drains lgkmcnt (ds_write visibility) but leaves global
// loads in flight across the barrier (unlike __syncthreads' vmcnt(0) drain).
#define LDSBAR do { asm volatile("s_waitcnt lgkmcnt(0)" ::: "memory"); \
                    __builtin_amdgcn_s_barrier(); \
                    asm volatile("" ::: "memory"); \
                    __builtin_amdgcn_sched_barrier(0); } while (0)

// ---------------------------------------------------------------------------
// dtype detect: t_steps[0..1] as one 32-bit word. bf16: [0, bf16(0.05)] ->
// 0x3D4D0000 != 0.  f32: first float 0.0f -> 0x00000000.
// flag = 1 means inputs are f32.
// ---------------------------------------------------------------------------
__global__ void detect_kernel(const unsigned* __restrict__ ts, int* __restrict__ flag) {
    if (threadIdx.x == 0 && blockIdx.x == 0) flag[0] = (ts[0] == 0u) ? 1 : 0;
}

struct ConvArgs { const void* src[NSEG]; };

__global__ __launch_bounds__(256) void convert_kernel(ConvArgs a, s16* __restrict__ dst,
                                                      const int* __restrict__ flag) {
    const int f = flag[0];
    for (int i = blockIdx.x * 256 + threadIdx.x; i < kTotalConv; i += gridDim.x * 256) {
        int s = 0;
        #pragma unroll
        for (int j = 1; j < NSEG; ++j) if (i >= kOff[j]) s = j;
        int local = i - kOff[s];
        s16 v;
        if (f) v = f2bs(((const float*)a.src[s])[local]);
        else   v = ((const s16*)a.src[s])[local];
        dst[i] = v;
    }
}

// ============================================================================
// ODE kernel: 64 blocks x 1024 threads (16 waves = 4/SIMD). Block owns 16
// rows of B. Wave w owns h-cols [w*16,w*16+16) for GEMM1/2 and out-cols
// [w*32,w*32+32) for GEMM3.
// ROUND-9 POSTMORTEM FIX: plain launch_bounds(1024) let the allocator cap at
// 64 VGPR (8-wave-occupancy target) and spill the asm batch arrays — the
// pipeline never existed. Now:
//   * __launch_bounds__(1024, 4): 4 waves/EU declared -> 128-VGPR budget.
//   * 4 rotating 4-frag buffers (bA..bD, 64 VGPR total), 3 slices (12 loads)
//     in flight, retired oldest-first with counted vmcnt. Peak live ~110.
//   * slice ledger (incl. e==3's 8 stores): loop-top VMWAIT(8) retires
//     stores+sliceA exactly; buffer reuse strictly after consumption.
//   * LDSBAR (lgkmcnt-only barrier) keeps slices in flight across barriers.
// ============================================================================
__global__ __launch_bounds__(1024, 4) void ode_kernel(
    const s16* __restrict__ zin, const s16* __restrict__ ts,
    const s16* __restrict__ W1, const s16* __restrict__ b1,
    const s16* __restrict__ W2, const s16* __restrict__ b2,
    const s16* __restrict__ W3, const s16* __restrict__ b3,
    s16* __restrict__ stage)
{
    __shared__ __align__(16) s16 sArg[16 * 520];   // [16][520]
    __shared__ __align__(16) s16 sH1[16 * 264];    // [16][264]
    __shared__ __align__(16) s16 sH2[16 * 264];    // [16][264]
    __shared__ float sScale[16];

    const int tid = threadIdx.x;
    const int w = tid >> 6;          // wave 0..15
    const int lane = tid & 63;
    const int quad = lane >> 4;
    const int c = lane & 15;
    const int r0 = blockIdx.x * 16;

    const float dt  = bs2f(ts[1]) - bs2f(ts[0]);
    const float hdt = 0.5f * dt;
    const float dt6 = dt / 6.0f;

    // ---- per-row adaptive scale (wave w handles row w) ----
    {
        const s16* zrow = zin + (size_t)(r0 + w) * kD;
        float sum = 0.f, ssq = 0.f;
        for (int i = 0; i < 8; ++i) {
            float v = bs2f(zrow[lane + 64 * i]);
            sum += v; ssq += v * v;
        }
        for (int m = 1; m < 64; m <<= 1) {
            sum += __shfl_xor(sum, m, 64);
            ssq += __shfl_xor(ssq, m, 64);
        }
        float zn = sqrtf(ssq);
        float mean = sum / (float)kD;
        float var = (ssq - (float)kD * mean * mean) / (float)(kD - 1); // ddof=1
        float sc = zn / (var + 1e-6f);
        sc = fminf(fmaxf(sc, 0.8f), 1.2f);
        if (lane == 0) sScale[w] = sc;
    }
    __syncthreads();

    // ---- z registers: wave w owns cols [w*32, w*32+32) ----
    const int colbase = w * 32;
    float zreg[2][4], accR[2][4];
    #pragma unroll
    for (int nt = 0; nt < 2; ++nt)
        #pragma unroll
        for (int rr = 0; rr < 4; ++rr) {
            int m = quad * 4 + rr, col = colbase + nt * 16 + c;
            zreg[nt][rr] = bs2f(zin[(size_t)(r0 + m) * kD + col]) * sScale[m];
            accR[nt][rr] = 0.f;
        }
    // ---- initial arg = bf16(z0): wave w fills row w ----
    {
        const s16* zrow = zin + (size_t)(r0 + w) * kD;
        float sc = sScale[w];
        s16* dst = sArg + w * 520 + lane * 8;
        #pragma unroll
        for (int j = 0; j < 8; ++j) dst[j] = f2bs(bs2f(zrow[lane * 8 + j]) * sc);
    }
    const float b1v = bs2f(b1[w * 16 + c]);
    const float b2v = bs2f(b2[w * 16 + c]);
    float b3v[2];
    b3v[0] = bs2f(b3[colbase + c]);
    b3v[1] = bs2f(b3[colbase + 16 + c]);

    // per-lane weight base pointers (asm offsets are bytes, 13-bit signed)
    const s16* w1p  = W1 + (size_t)(w * 16 + c) * kD + quad * 8;
    const s16* w2p  = W2 + (size_t)(w * 16 + c) * kH + quad * 8;
    const s16* w3p0 = W3 + (size_t)(w * 32 + c) * kH + quad * 8;
    const s16* w3p1 = w3p0 + 16 * kH;

    __syncthreads();

    #pragma unroll 1
    for (int t = 0; t < kT; ++t) {
        #pragma unroll 1
        for (int e = 0; e < 4; ++e) {
            bf16x8 bA[4], bB[4], bC[4], bD[4];   // rotating slice buffers
            // ---- issue W1 slices A,B,C (12 in flight) ----
            GLD(bA[0], w1p, 0);   GLD(bA[1], w1p, 64);
            GLD(bA[2], w1p, 128); GLD(bA[3], w1p, 192);
            GLD(bB[0], w1p, 256); GLD(bB[1], w1p, 320);
            GLD(bB[2], w1p, 384); GLD(bB[3], w1p, 448);
            GLD(bC[0], w1p, 512); GLD(bC[1], w1p, 576);
            GLD(bC[2], w1p, 640); GLD(bC[3], w1p, 704);
            VMWAIT(8);   // retires prior stores + slice A
            f32x4 a1 = {0.f, 0.f, 0.f, 0.f};
            #pragma unroll
            for (int kk = 0; kk < 4; ++kk) {
                bf16x8 av = *(const bf16x8*)(sArg + c * 520 + kk * 32 + quad * 8);
                a1 = mfma16(av, bA[kk], a1);
            }
            GLD(bD[0], w1p, 768); GLD(bD[1], w1p, 832);
            GLD(bD[2], w1p, 896); GLD(bD[3], w1p, 960);
            VMWAIT(8);   // B ready
            #pragma unroll
            for (int kk = 4; kk < 8; ++kk) {
                bf16x8 av = *(const bf16x8*)(sArg + c * 520 + kk * 32 + quad * 8);
                a1 = mfma16(av, bB[kk - 4], a1);
            }
            GLD(bA[0], w2p, 0);   GLD(bA[1], w2p, 64);     // slice E (W2 kk0-3)
            GLD(bA[2], w2p, 128); GLD(bA[3], w2p, 192);
            VMWAIT(8);   // C ready
            #pragma unroll
            for (int kk = 8; kk < 12; ++kk) {
                bf16x8 av = *(const bf16x8*)(sArg + c * 520 + kk * 32 + quad * 8);
                a1 = mfma16(av, bC[kk - 8], a1);
            }
            GLD(bB[0], w2p, 256); GLD(bB[1], w2p, 320);    // slice F (W2 kk4-7)
            GLD(bB[2], w2p, 384); GLD(bB[3], w2p, 448);
            VMWAIT(8);   // D ready
            #pragma unroll
            for (int kk = 12; kk < 16; ++kk) {
                bf16x8 av = *(const bf16x8*)(sArg + c * 520 + kk * 32 + quad * 8);
                a1 = mfma16(av, bD[kk - 12], a1);
            }
            GLD(bC[0], w3p0, 0);  GLD(bC[1], w3p1, 0);     // slice G (W3 kk0-1)
            GLD(bC[2], w3p0, 64); GLD(bC[3], w3p1, 64);
            #pragma unroll
            for (int rr = 0; rr < 4; ++rr)
                sH1[(quad * 4 + rr) * 264 + w * 16 + c] = f2bs(gelu(a1[rr] + b1v));
            LDSBAR;      // E,F,G stay in flight

            // ===== Phase 2: GEMM2 (K=256) =====
            VMWAIT(8);   // E ready
            f32x4 a2 = {0.f, 0.f, 0.f, 0.f};
            #pragma unroll
            for (int kk = 0; kk < 4; ++kk) {
                bf16x8 av = *(const bf16x8*)(sH1 + c * 264 + kk * 32 + quad * 8);
                a2 = mfma16(av, bA[kk], a2);
            }
            GLD(bD[0], w3p0, 128); GLD(bD[1], w3p1, 128);  // slice H (W3 kk2-3)
            GLD(bD[2], w3p0, 192); GLD(bD[3], w3p1, 192);
            VMWAIT(8);   // F ready
            #pragma unroll
            for (int kk = 4; kk < 8; ++kk) {
                bf16x8 av = *(const bf16x8*)(sH1 + c * 264 + kk * 32 + quad * 8);
                a2 = mfma16(av, bB[kk - 4], a2);
            }
            GLD(bA[0], w3p0, 256); GLD(bA[1], w3p1, 256);  // slice I (W3 kk4-5)
            GLD(bA[2], w3p0, 320); GLD(bA[3], w3p1, 320);
            #pragma unroll
            for (int rr = 0; rr < 4; ++rr)
                sH2[(quad * 4 + rr) * 264 + w * 16 + c] = f2bs(gelu(a2[rr] + b2v));
            LDSBAR;      // G,H,I stay in flight

            // ===== Phase 3: GEMM3 (K=256), 2 n-tiles =====
            f32x4 a30 = {0.f, 0.f, 0.f, 0.f}, a31 = {0.f, 0.f, 0.f, 0.f};
            VMWAIT(8);   // G ready
            {
                bf16x8 av0 = *(const bf16x8*)(sH2 + c * 264 + 0 * 32 + quad * 8);
                a30 = mfma16(av0, bC[0], a30); a31 = mfma16(av0, bC[1], a31);
                bf16x8 av1 = *(const bf16x8*)(sH2 + c * 264 + 1 * 32 + quad * 8);
                a30 = mfma16(av1, bC[2], a30); a31 = mfma16(av1, bC[3], a31);
            }
            GLD(bB[0], w3p0, 384); GLD(bB[1], w3p1, 384);  // slice J (W3 kk6-7)
            GLD(bB[2], w3p0, 448); GLD(bB[3], w3p1, 448);
            VMWAIT(8);   // H ready
            {
                bf16x8 av2 = *(const bf16x8*)(sH2 + c * 264 + 2 * 32 + quad * 8);
                a30 = mfma16(av2, bD[0], a30); a31 = mfma16(av2, bD[1], a31);
                bf16x8 av3 = *(const bf16x8*)(sH2 + c * 264 + 3 * 32 + quad * 8);
                a30 = mfma16(av3, bD[2], a30); a31 = mfma16(av3, bD[3], a31);
            }
            VMWAIT(4);   // I ready
            {
                bf16x8 av4 = *(const bf16x8*)(sH2 + c * 264 + 4 * 32 + quad * 8);
                a30 = mfma16(av4, bA[0], a30); a31 = mfma16(av4, bA[1], a31);
                bf16x8 av5 = *(const bf16x8*)(sH2 + c * 264 + 5 * 32 + quad * 8);
                a30 = mfma16(av5, bA[2], a30); a31 = mfma16(av5, bA[3], a31);
            }
            VMWAIT(0);   // J ready
            {
                bf16x8 av6 = *(const bf16x8*)(sH2 + c * 264 + 6 * 32 + quad * 8);
                a30 = mfma16(av6, bB[0], a30); a31 = mfma16(av6, bB[1], a31);
                bf16x8 av7 = *(const bf16x8*)(sH2 + c * 264 + 7 * 32 + quad * 8);
                a30 = mfma16(av7, bB[2], a30); a31 = mfma16(av7, bB[3], a31);
            }

            // ===== RK4 accumulate / advance =====
            const float wsum = (e == 0 || e == 3) ? 1.f : 2.f;
            const float cstep = (e == 2) ? dt : hdt;
            #pragma unroll
            for (int nt = 0; nt < 2; ++nt) {
                #pragma unroll
                for (int rr = 0; rr < 4; ++rr) {
                    float fv = ((nt == 0) ? a30[rr] : a31[rr]) + b3v[nt];
                    accR[nt][rr] += wsum * fv;
                    int m = quad * 4 + rr;
                    int col = colbase + nt * 16 + c;
                    float argv;
                    if (e < 3) {
                        argv = zreg[nt][rr] + cstep * fv;
                    } else {
                        float zn2 = zreg[nt][rr] + dt6 * accR[nt][rr];
                        zn2 = (zn2 != zn2) ? 0.f : zn2;  // NaN guard
                        zreg[nt][rr] = zn2;
                        accR[nt][rr] = 0.f;
                        argv = zn2;
                        stage[(size_t)(r0 + m) * kT * kD + (size_t)t * kD + col] = f2bs(zn2);
                    }
                    sArg[m * 520 + col] = f2bs(argv);
                }
            }
            LDSBAR;
        }
    }
}

// ============================================================================
// Attention kernel: 1024 blocks (one per batch row) x 256 threads (4 waves).
// Reads z_stack from stage; writes z_final to outp (bf16 or f32 per flag).
// Static LDS 55.3 KB. P and ctx overlay the dead Q buffer.
// ============================================================================
__global__ __launch_bounds__(256) void attn_kernel(
    const s16* __restrict__ zin,
    const s16* __restrict__ Wqkv, const s16* __restrict__ bqkv,
    const s16* __restrict__ Wo, const s16* __restrict__ bo,
    const s16* __restrict__ gm, const s16* __restrict__ bt,
    const s16* __restrict__ stage, void* __restrict__ outp,
    const int* __restrict__ flag, int mode)
{
    __shared__ __align__(16) s16 sQ[64 * 136];   // Q -> P -> ctx (per-wave rows)
    __shared__ __align__(16) s16 sK[64 * 136];
    __shared__ __align__(16) s16 sVT[128 * 72];  // V transposed [d][t]
    __shared__ __align__(16) s16 sMean[512];
    __shared__ __align__(16) s16 sZi[512];
    float* psum = (float*)sQ;                    // preamble overlay: [4][512] f32 (8 KB < 17.4 KB)

    const int tid = threadIdx.x;
    const int w = tid >> 6, lane = tid & 63, quad = lane >> 4, c = lane & 15;
    const int b = blockIdx.x;
    const int f32out = mode ? flag[0] : 0;
    const s16* zs = stage + (size_t)b * kT * kD;   // this block's z_stack [64][512]

    // ---- preamble: z_init row; column means of z_stack over T ----
    for (int i = tid; i < kD; i += 256) sZi[i] = zin[(size_t)b * kD + i];
    {
        float s[8] = {0, 0, 0, 0, 0, 0, 0, 0};
        const int phase = tid >> 6, cg = (tid & 63) * 8;
        for (int i = 0; i < 16; ++i) {
            int t = phase + 4 * i;
            bf16x8 v = *(const bf16x8*)(zs + (size_t)t * kD + cg);
            #pragma unroll
            for (int j = 0; j < 8; ++j) s[j] += bs2f(v[j]);
        }
        #pragma unroll
        for (int j = 0; j < 8; ++j) psum[phase * kD + cg + j] = s[j];
    }
    __syncthreads();
    for (int col = tid; col < kD; col += 256) {
        float m = (psum[col] + psum[kD + col] + psum[2 * kD + col] + psum[3 * kD + col]) * (1.f / 64.f);
        sMean[col] = f2bs(m);
    }
    __syncthreads();

    // ---- A-fragments of z_dc for this wave's 16 rows (t = w*16 + c) ----
    bf16x8 afrag[16];
    #pragma unroll
    for (int kk = 0; kk < 16; ++kk) {
        int k0 = kk * 32 + quad * 8;
        bf16x8 zv = *(const bf16x8*)(zs + (size_t)(w * 16 + c) * kD + k0);
        bf16x8 o;
        #pragma unroll
        for (int j = 0; j < 8; ++j) {
            float zd = bs2f(zv[j]) - 0.05f * (bs2f(sMean[k0 + j]) - bs2f(sZi[k0 + j]));
            o[j] = f2bs(zd);
        }
        afrag[kk] = o;
    }

    f32x4 xacc[32];
    #pragma unroll
    for (int nt = 0; nt < 32; ++nt) xacc[nt] = {0.f, 0.f, 0.f, 0.f};

    const float iscl = 0.08838834764831845f;  // 1/sqrt(128)

    for (int h = 0; h < 4; ++h) {
        __syncthreads();  // protect sQ/sK/sVT rewrite vs prior head's readers
        // ---- qkv for head h: mat 0=Q, 1=K, 2=V ----
        for (int mat = 0; mat < 3; ++mat) {
            f32x4 acc[8];
            #pragma unroll
            for (int nt = 0; nt < 8; ++nt) acc[nt] = {0.f, 0.f, 0.f, 0.f};
            const s16* Wbase = Wqkv + (size_t)(mat * 512 + h * 128 + c) * kD + quad * 8;
            #pragma unroll
            for (int kk = 0; kk < 16; ++kk) {
                bf16x8 a = afrag[kk];
                #pragma unroll
                for (int nt = 0; nt < 8; ++nt) {
                    bf16x8 bb = *(const bf16x8*)(Wbase + (size_t)(nt * 16) * kD + kk * 32);
                    acc[nt] = mfma16(a, bb, acc[nt]);
                }
            }
            #pragma unroll
            for (int nt = 0; nt < 8; ++nt)
                #pragma unroll
                for (int rr = 0; rr < 4; ++rr) {
                    int n = h * 128 + nt * 16 + c;
                    float v = acc[nt][rr] + bs2f(bqkv[mat * 512 + n]);
                    int trow = w * 16 + quad * 4 + rr, dcol = nt * 16 + c;
                    if (mat == 0)      sQ[trow * 136 + dcol] = f2bs(v);
                    else if (mat == 1) sK[trow * 136 + dcol] = f2bs(v);
                    else               sVT[dcol * 72 + trow] = f2bs(v);
                }
        }
        __syncthreads();

        // ---- S = Q K^T (wave's 16 q-rows x 64 k-cols) ----
        f32x4 sfr[4];
        #pragma unroll
        for (int nt = 0; nt < 4; ++nt) sfr[nt] = {0.f, 0.f, 0.f, 0.f};
        #pragma unroll
        for (int kk = 0; kk < 4; ++kk) {
            bf16x8 a = *(const bf16x8*)(sQ + (w * 16 + c) * 136 + kk * 32 + quad * 8);
            #pragma unroll
            for (int nt = 0; nt < 4; ++nt) {
                bf16x8 bb = *(const bf16x8*)(sK + (nt * 16 + c) * 136 + kk * 32 + quad * 8);
                sfr[nt] = mfma16(a, bb, sfr[nt]);
            }
        }
        // ---- softmax along k (within quad: 16 lanes x 4 regs) ----
        #pragma unroll
        for (int rr = 0; rr < 4; ++rr) {
            float v[4];
            #pragma unroll
            for (int nt = 0; nt < 4; ++nt) v[nt] = sfr[nt][rr] * iscl;
            float mx = fmaxf(fmaxf(v[0], v[1]), fmaxf(v[2], v[3]));
            for (int m = 1; m < 16; m <<= 1) mx = fmaxf(mx, __shfl_xor(mx, m, 64));
            float sm = 0.f;
            #pragma unroll
            for (int nt = 0; nt < 4; ++nt) { v[nt] = __expf(v[nt] - mx); sm += v[nt]; }
            for (int m = 1; m < 16; m <<= 1) sm += __shfl_xor(sm, m, 64);
            float inv = 1.0f / sm;
            // P overlays dead Q (own rows only; no wave reads another wave's Q rows)
            #pragma unroll
            for (int nt = 0; nt < 4; ++nt)
                sQ[(w * 16 + quad * 4 + rr) * 136 + nt * 16 + c] = f2bs(v[nt] * inv);
        }
        // ---- ctx_h = P @ V  (K=64) ----
        f32x4 o[8];
        #pragma unroll
        for (int nt = 0; nt < 8; ++nt) o[nt] = {0.f, 0.f, 0.f, 0.f};
        #pragma unroll
        for (int kk = 0; kk < 2; ++kk) {
            bf16x8 a = *(const bf16x8*)(sQ + (w * 16 + c) * 136 + kk * 32 + quad * 8);
            #pragma unroll
            for (int nt = 0; nt < 8; ++nt) {
                bf16x8 bb = *(const bf16x8*)(sVT + (nt * 16 + c) * 72 + kk * 32 + quad * 8);
                o[nt] = mfma16(a, bb, o[nt]);
            }
        }
        // ctx_h -> sQ (own rows; P consumed)
        #pragma unroll
        for (int nt = 0; nt < 8; ++nt)
            #pragma unroll
            for (int rr = 0; rr < 4; ++rr)
                sQ[(w * 16 + quad * 4 + rr) * 136 + nt * 16 + c] = f2bs(o[nt][rr]);
        // ---- out-proj partial: x += ctx_h @ Wo[:, h*128:+128]^T ----
        #pragma unroll
        for (int kk = 0; kk < 4; ++kk) {
            bf16x8 a = *(const bf16x8*)(sQ + (w * 16 + c) * 136 + kk * 32 + quad * 8);
            #pragma unroll
            for (int nt = 0; nt < 32; ++nt) {
                bf16x8 bb = *(const bf16x8*)(Wo + (size_t)(nt * 16 + c) * kD + h * 128 + kk * 32 + quad * 8);
                xacc[nt] = mfma16(a, bb, xacc[nt]);
            }
        }
    }

    // ---- epilogue: x = z_dc + att_out + bo; LayerNorm; store ----
    float sum[4] = {0, 0, 0, 0}, ssq[4] = {0, 0, 0, 0};
    #pragma unroll
    for (int nt = 0; nt < 32; ++nt)
        #pragma unroll
        for (int rr = 0; rr < 4; ++rr) {
            int trow = w * 16 + quad * 4 + rr;
            int col = nt * 16 + c;
            float zd = bs2f(zs[(size_t)trow * kD + col]) - 0.05f * (bs2f(sMean[col]) - bs2f(sZi[col]));
            float x = xacc[nt][rr] + bs2f(bo[col]) + zd;
            xacc[nt][rr] = x;
            sum[rr] += x; ssq[rr] += x * x;
        }
    float mu[4], rstd[4];
    #pragma unroll
    for (int rr = 0; rr < 4; ++rr) {
        float s = sum[rr], q = ssq[rr];
        for (int m = 1; m < 16; m <<= 1) { s += __shfl_xor(s, m, 64); q += __shfl_xor(q, m, 64); }
        float mm = s / (float)kD;
        float var = q / (float)kD - mm * mm;   // biased, eps 1e-5
        mu[rr] = mm;
        rstd[rr] = rsqrtf(var + 1e-5f);
    }
    #pragma unroll
    for (int nt = 0; nt < 32; ++nt)
        #pragma unroll
        for (int rr = 0; rr < 4; ++rr) {
            int trow = w * 16 + quad * 4 + rr;
            int col = nt * 16 + c;
            float v = (xacc[nt][rr] - mu[rr]) * rstd[rr] * bs2f(gm[col]) + bs2f(bt[col]);
            v = (v != v) ? 0.f : v;
            size_t idx = ((size_t)b * kT + trow) * kD + col;
            if (f32out) ((float*)outp)[idx] = v;
            else        ((s16*)outp)[idx] = f2bs(v);
        }
}

extern "C" void kernel_launch(void* const* d_in, const int* in_sizes, int n_in,
                              void* d_out, int out_size, void* d_ws, size_t ws_size,
                              hipStream_t stream) {
    (void)in_sizes; (void)n_in; (void)out_size;
    const size_t kStageElems = (size_t)kB * kT * kD;
    const size_t kNeed = 16 + (size_t)kTotalConv * 2 + kStageElems * 2;   // ~70.9 MB

    const s16* p[NSEG];
    s16* stage;
    void* outp = d_out;
    const int* flag = nullptr;
    int mode = 0;

    if (ws_size >= kNeed) {
        int* flg = (int*)d_ws;
        s16* conv = (s16*)((char*)d_ws + 16);
        stage = (s16*)((char*)d_ws + 16 + (size_t)kTotalConv * 2);
        detect_kernel<<<dim3(1), dim3(64), 0, stream>>>((const unsigned*)d_in[1], flg);
        ConvArgs ca;
        for (int i = 0; i < NSEG; ++i) ca.src[i] = d_in[i];
        convert_kernel<<<dim3(512), dim3(256), 0, stream>>>(ca, conv, flg);
        for (int i = 0; i < NSEG; ++i) p[i] = conv + kOff[i];
        flag = flg;
        mode = 1;
    } else {
        for (int i = 0; i < NSEG; ++i) p[i] = (const s16*)d_in[i];
        stage = (s16*)d_out;   // in-place staging (bf16 assumed)
    }

    ode_kernel<<<dim3(64), dim3(1024), 0, stream>>>(
        p[0], p[1], p[2], p[3], p[4], p[5], p[6], p[7], stage);
    attn_kernel<<<dim3(kB), dim3(256), 0, stream>>>(
        p[0], p[8], p[9], p[10], p[11], p[12], p[13], stage, outp, flag, mode);
}

// Round 12
// 5118.320 us; speedup vs baseline: 1.3110x; 1.3058x over previous
//
#include <hip/hip_runtime.h>

typedef short s16;
typedef short bf16x8 __attribute__((ext_vector_type(8)));
typedef float f32x4 __attribute__((ext_vector_type(4)));

constexpr int kB = 1024, kT = 64, kD = 512, kH = 256;
constexpr int NSEG = 14;
// element counts per input (setup_inputs order) and exclusive prefix offsets
// z_init t  W1     b1  W2    b2  W3     b3  Wqkv   bqkv Wo     bo  gamma beta
// 524288 64 131072 256 65536 256 131072 512 786432 1536 262144 512 512   512
constexpr int kOff[NSEG] = {0, 524288, 524352, 655424, 655680, 721216, 721472,
                            852544, 853056, 1639488, 1641024, 1903168, 1903680, 1904192};
constexpr int kTotalConv = 1904704;

__device__ __forceinline__ float bs2f(s16 s) {
    return __uint_as_float(((unsigned)(unsigned short)s) << 16);
}
__device__ __forceinline__ s16 f2bs(float f) {
    unsigned u = __float_as_uint(f);
    unsigned r = (u + 0x7fffu + ((u >> 16) & 1u)) >> 16;
    return (s16)r;
}
__device__ __forceinline__ f32x4 mfma16(bf16x8 a, bf16x8 b, f32x4 c) {
    return __builtin_amdgcn_mfma_f32_16x16x32_bf16(a, b, c, 0, 0, 0);
}
__device__ __forceinline__ float gelu(float x) {
    return 0.5f * x * (1.0f + erff(x * 0.70710678118654752f));
}

// ---------------------------------------------------------------------------
// dtype detect: t_steps[0..1] as one 32-bit word. bf16: [0, bf16(0.05)] ->
// 0x3D4D0000 != 0.  f32: first float 0.0f -> 0x00000000.
// flag = 1 means inputs are f32.
// ---------------------------------------------------------------------------
__global__ void detect_kernel(const unsigned* __restrict__ ts, int* __restrict__ flag) {
    if (threadIdx.x == 0 && blockIdx.x == 0) flag[0] = (ts[0] == 0u) ? 1 : 0;
}

struct ConvArgs { const void* src[NSEG]; };

__global__ __launch_bounds__(256) void convert_kernel(ConvArgs a, s16* __restrict__ dst,
                                                      const int* __restrict__ flag) {
    const int f = flag[0];
    for (int i = blockIdx.x * 256 + threadIdx.x; i < kTotalConv; i += gridDim.x * 256) {
        int s = 0;
        #pragma unroll
        for (int j = 1; j < NSEG; ++j) if (i >= kOff[j]) s = j;
        int local = i - kOff[s];
        s16 v;
        if (f) v = f2bs(((const float*)a.src[s])[local]);
        else   v = ((const s16*)a.src[s])[local];
        dst[i] = v;
    }
}

// ============================================================================
// ODE kernel: 64 blocks x 1024 threads (16 waves = 4/SIMD). Block owns 16
// rows of B. z state in registers (f32), field arg / h1 / h2 in LDS (bf16).
// REVERTED to the session-best compiler-scheduled form (measured 5115 µs
// total in the prior session; best of 10 tested variants this session).
// Evidence for revert: hipcc caps 1024-thread blocks at 64 VGPR (r9/r10 both
// 64 despite launch_bounds(1024,4)) -> explicit register pipelines spill;
// 8-wave variants (128 VGPR) lose more TLP than pipelining gains
// (4050-4430 µs vs ~3100 µs here). The compiler's one-load-per-MFMA
// schedule + 4 waves/SIMD is the local optimum under this constraint.
// Writes z_stack [B,T,D] bf16 into stage.
// ============================================================================
__global__ __launch_bounds__(1024) void ode_kernel(
    const s16* __restrict__ zin, const s16* __restrict__ ts,
    const s16* __restrict__ W1, const s16* __restrict__ b1,
    const s16* __restrict__ W2, const s16* __restrict__ b2,
    const s16* __restrict__ W3, const s16* __restrict__ b3,
    s16* __restrict__ stage)
{
    __shared__ __align__(16) s16 sArg[16 * 520];   // [16][520]
    __shared__ __align__(16) s16 sH1[16 * 264];    // [16][264]
    __shared__ __align__(16) s16 sH2[16 * 264];    // [16][264]
    __shared__ float sScale[16];

    const int tid = threadIdx.x;
    const int w = tid >> 6;          // wave 0..15
    const int lane = tid & 63;
    const int quad = lane >> 4;
    const int c = lane & 15;
    const int r0 = blockIdx.x * 16;

    const float dt  = bs2f(ts[1]) - bs2f(ts[0]);
    const float hdt = 0.5f * dt;
    const float dt6 = dt / 6.0f;

    // ---- per-row adaptive scale (wave w handles row w) ----
    {
        const s16* zrow = zin + (size_t)(r0 + w) * kD;
        float sum = 0.f, ssq = 0.f;
        for (int i = 0; i < 8; ++i) {
            float v = bs2f(zrow[lane + 64 * i]);
            sum += v; ssq += v * v;
        }
        for (int m = 1; m < 64; m <<= 1) {
            sum += __shfl_xor(sum, m, 64);
            ssq += __shfl_xor(ssq, m, 64);
        }
        float zn = sqrtf(ssq);
        float mean = sum / (float)kD;
        float var = (ssq - (float)kD * mean * mean) / (float)(kD - 1); // ddof=1
        float sc = zn / (var + 1e-6f);
        sc = fminf(fmaxf(sc, 0.8f), 1.2f);
        if (lane == 0) sScale[w] = sc;
    }
    __syncthreads();

    // ---- z registers: wave w owns cols [w*32, w*32+32). C-layout (m=quad*4+rr, col) ----
    const int colbase = w * 32;
    float zreg[2][4], accR[2][4];
    #pragma unroll
    for (int nt = 0; nt < 2; ++nt)
        #pragma unroll
        for (int rr = 0; rr < 4; ++rr) {
            int m = quad * 4 + rr, col = colbase + nt * 16 + c;
            zreg[nt][rr] = bs2f(zin[(size_t)(r0 + m) * kD + col]) * sScale[m];
            accR[nt][rr] = 0.f;
        }
    // ---- initial arg = bf16(z0): wave w fills row w ----
    {
        const s16* zrow = zin + (size_t)(r0 + w) * kD;
        float sc = sScale[w];
        s16* dst = sArg + w * 520 + lane * 8;
        #pragma unroll
        for (int j = 0; j < 8; ++j) dst[j] = f2bs(bs2f(zrow[lane * 8 + j]) * sc);
    }
    const float b1v = bs2f(b1[w * 16 + c]);
    const float b2v = bs2f(b2[w * 16 + c]);
    const float b3v0 = bs2f(b3[colbase + c]);
    const float b3v1 = bs2f(b3[colbase + 16 + c]);
    __syncthreads();

    #pragma unroll 1
    for (int t = 0; t < kT; ++t) {
        #pragma unroll 1
        for (int e = 0; e < 4; ++e) {
            // GEMM1: h1[n = w*16+c], K=512
            f32x4 a1 = {0.f, 0.f, 0.f, 0.f};
            {
                const bf16x8* Ap = (const bf16x8*)(sArg + c * 520 + quad * 8);
                const bf16x8* Bp = (const bf16x8*)(W1 + (size_t)(w * 16 + c) * kD + quad * 8);
                #pragma unroll
                for (int kk = 0; kk < 16; ++kk)
                    a1 = mfma16(Ap[kk * 4], Bp[kk * 4], a1);
            }
            #pragma unroll
            for (int rr = 0; rr < 4; ++rr)
                sH1[(quad * 4 + rr) * 264 + w * 16 + c] = f2bs(gelu(a1[rr] + b1v));
            __syncthreads();

            // GEMM2: K=256
            f32x4 a2 = {0.f, 0.f, 0.f, 0.f};
            {
                const bf16x8* Ap = (const bf16x8*)(sH1 + c * 264 + quad * 8);
                const bf16x8* Bp = (const bf16x8*)(W2 + (size_t)(w * 16 + c) * kH + quad * 8);
                #pragma unroll
                for (int kk = 0; kk < 8; ++kk)
                    a2 = mfma16(Ap[kk * 4], Bp[kk * 4], a2);
            }
            #pragma unroll
            for (int rr = 0; rr < 4; ++rr)
                sH2[(quad * 4 + rr) * 264 + w * 16 + c] = f2bs(gelu(a2[rr] + b2v));
            __syncthreads();

            // GEMM3: cols colbase..colbase+31, K=256
            f32x4 a3n0 = {0.f, 0.f, 0.f, 0.f}, a3n1 = {0.f, 0.f, 0.f, 0.f};
            {
                const bf16x8* Ap = (const bf16x8*)(sH2 + c * 264 + quad * 8);
                const bf16x8* B0 = (const bf16x8*)(W3 + (size_t)(colbase + c) * kH + quad * 8);
                const bf16x8* B1 = (const bf16x8*)(W3 + (size_t)(colbase + 16 + c) * kH + quad * 8);
                #pragma unroll
                for (int kk = 0; kk < 8; ++kk) {
                    bf16x8 av = Ap[kk * 4];
                    a3n0 = mfma16(av, B0[kk * 4], a3n0);
                    a3n1 = mfma16(av, B1[kk * 4], a3n1);
                }
            }
            const float wsum = (e == 0 || e == 3) ? 1.f : 2.f;
            const float cstep = (e == 2) ? dt : hdt;
            #pragma unroll
            for (int nt = 0; nt < 2; ++nt) {
                #pragma unroll
                for (int rr = 0; rr < 4; ++rr) {
                    float fv = ((nt == 0) ? a3n0[rr] : a3n1[rr]) + ((nt == 0) ? b3v0 : b3v1);
                    accR[nt][rr] += wsum * fv;
                    int m = quad * 4 + rr;
                    int col = colbase + nt * 16 + c;
                    float argv;
                    if (e < 3) {
                        argv = zreg[nt][rr] + cstep * fv;
                    } else {
                        float zn2 = zreg[nt][rr] + dt6 * accR[nt][rr];
                        zn2 = (zn2 != zn2) ? 0.f : zn2;  // NaN guard
                        zreg[nt][rr] = zn2;
                        accR[nt][rr] = 0.f;
                        argv = zn2;
                        stage[(size_t)(r0 + m) * kT * kD + (size_t)t * kD + col] = f2bs(zn2);
                    }
                    sArg[m * 520 + col] = f2bs(argv);
                }
            }
            __syncthreads();
        }
    }
}

// ============================================================================
// Attention kernel: 1024 blocks (one per batch row) x 256 threads (4 waves).
// Reads z_stack from stage; writes z_final to outp (bf16 or f32 per flag).
// Static LDS 55.3 KB. P and ctx overlay the dead Q buffer.
// ============================================================================
__global__ __launch_bounds__(256) void attn_kernel(
    const s16* __restrict__ zin,
    const s16* __restrict__ Wqkv, const s16* __restrict__ bqkv,
    const s16* __restrict__ Wo, const s16* __restrict__ bo,
    const s16* __restrict__ gm, const s16* __restrict__ bt,
    const s16* __restrict__ stage, void* __restrict__ outp,
    const int* __restrict__ flag, int mode)
{
    __shared__ __align__(16) s16 sQ[64 * 136];   // Q -> P -> ctx (per-wave rows)
    __shared__ __align__(16) s16 sK[64 * 136];
    __shared__ __align__(16) s16 sVT[128 * 72];  // V transposed [d][t]
    __shared__ __align__(16) s16 sMean[512];
    __shared__ __align__(16) s16 sZi[512];
    float* psum = (float*)sQ;                    // preamble overlay: [4][512] f32 (8 KB < 17.4 KB)

    const int tid = threadIdx.x;
    const int w = tid >> 6, lane = tid & 63, quad = lane >> 4, c = lane & 15;
    const int b = blockIdx.x;
    const int f32out = mode ? flag[0] : 0;
    const s16* zs = stage + (size_t)b * kT * kD;   // this block's z_stack [64][512]

    // ---- preamble: z_init row; column means of z_stack over T ----
    for (int i = tid; i < kD; i += 256) sZi[i] = zin[(size_t)b * kD + i];
    {
        float s[8] = {0, 0, 0, 0, 0, 0, 0, 0};
        const int phase = tid >> 6, cg = (tid & 63) * 8;
        for (int i = 0; i < 16; ++i) {
            int t = phase + 4 * i;
            bf16x8 v = *(const bf16x8*)(zs + (size_t)t * kD + cg);
            #pragma unroll
            for (int j = 0; j < 8; ++j) s[j] += bs2f(v[j]);
        }
        #pragma unroll
        for (int j = 0; j < 8; ++j) psum[phase * kD + cg + j] = s[j];
    }
    __syncthreads();
    for (int col = tid; col < kD; col += 256) {
        float m = (psum[col] + psum[kD + col] + psum[2 * kD + col] + psum[3 * kD + col]) * (1.f / 64.f);
        sMean[col] = f2bs(m);
    }
    __syncthreads();

    // ---- A-fragments of z_dc for this wave's 16 rows (t = w*16 + c) ----
    bf16x8 afrag[16];
    #pragma unroll
    for (int kk = 0; kk < 16; ++kk) {
        int k0 = kk * 32 + quad * 8;
        bf16x8 zv = *(const bf16x8*)(zs + (size_t)(w * 16 + c) * kD + k0);
        bf16x8 o;
        #pragma unroll
        for (int j = 0; j < 8; ++j) {
            float zd = bs2f(zv[j]) - 0.05f * (bs2f(sMean[k0 + j]) - bs2f(sZi[k0 + j]));
            o[j] = f2bs(zd);
        }
        afrag[kk] = o;
    }

    f32x4 xacc[32];
    #pragma unroll
    for (int nt = 0; nt < 32; ++nt) xacc[nt] = {0.f, 0.f, 0.f, 0.f};

    const float iscl = 0.08838834764831845f;  // 1/sqrt(128)

    for (int h = 0; h < 4; ++h) {
        __syncthreads();  // protect sQ/sK/sVT rewrite vs prior head's readers
        // ---- qkv for head h: mat 0=Q, 1=K, 2=V ----
        for (int mat = 0; mat < 3; ++mat) {
            f32x4 acc[8];
            #pragma unroll
            for (int nt = 0; nt < 8; ++nt) acc[nt] = {0.f, 0.f, 0.f, 0.f};
            const s16* Wbase = Wqkv + (size_t)(mat * 512 + h * 128 + c) * kD + quad * 8;
            #pragma unroll
            for (int kk = 0; kk < 16; ++kk) {
                bf16x8 a = afrag[kk];
                #pragma unroll
                for (int nt = 0; nt < 8; ++nt) {
                    bf16x8 bb = *(const bf16x8*)(Wbase + (size_t)(nt * 16) * kD + kk * 32);
                    acc[nt] = mfma16(a, bb, acc[nt]);
                }
            }
            #pragma unroll
            for (int nt = 0; nt < 8; ++nt)
                #pragma unroll
                for (int rr = 0; rr < 4; ++rr) {
                    int n = h * 128 + nt * 16 + c;
                    float v = acc[nt][rr] + bs2f(bqkv[mat * 512 + n]);
                    int trow = w * 16 + quad * 4 + rr, dcol = nt * 16 + c;
                    if (mat == 0)      sQ[trow * 136 + dcol] = f2bs(v);
                    else if (mat == 1) sK[trow * 136 + dcol] = f2bs(v);
                    else               sVT[dcol * 72 + trow] = f2bs(v);
                }
        }
        __syncthreads();

        // ---- S = Q K^T (wave's 16 q-rows x 64 k-cols) ----
        f32x4 sfr[4];
        #pragma unroll
        for (int nt = 0; nt < 4; ++nt) sfr[nt] = {0.f, 0.f, 0.f, 0.f};
        #pragma unroll
        for (int kk = 0; kk < 4; ++kk) {
            bf16x8 a = *(const bf16x8*)(sQ + (w * 16 + c) * 136 + kk * 32 + quad * 8);
            #pragma unroll
            for (int nt = 0; nt < 4; ++nt) {
                bf16x8 bb = *(const bf16x8*)(sK + (nt * 16 + c) * 136 + kk * 32 + quad * 8);
                sfr[nt] = mfma16(a, bb, sfr[nt]);
            }
        }
        // ---- softmax along k (within quad: 16 lanes x 4 regs) ----
        #pragma unroll
        for (int rr = 0; rr < 4; ++rr) {
            float v[4];
            #pragma unroll
            for (int nt = 0; nt < 4; ++nt) v[nt] = sfr[nt][rr] * iscl;
            float mx = fmaxf(fmaxf(v[0], v[1]), fmaxf(v[2], v[3]));
            for (int m = 1; m < 16; m <<= 1) mx = fmaxf(mx, __shfl_xor(mx, m, 64));
            float sm = 0.f;
            #pragma unroll
            for (int nt = 0; nt < 4; ++nt) { v[nt] = __expf(v[nt] - mx); sm += v[nt]; }
            for (int m = 1; m < 16; m <<= 1) sm += __shfl_xor(sm, m, 64);
            float inv = 1.0f / sm;
            // P overlays dead Q (own rows only; no wave reads another wave's Q rows)
            #pragma unroll
            for (int nt = 0; nt < 4; ++nt)
                sQ[(w * 16 + quad * 4 + rr) * 136 + nt * 16 + c] = f2bs(v[nt] * inv);
        }
        // ---- ctx_h = P @ V  (K=64) ----
        f32x4 o[8];
        #pragma unroll
        for (int nt = 0; nt < 8; ++nt) o[nt] = {0.f, 0.f, 0.f, 0.f};
        #pragma unroll
        for (int kk = 0; kk < 2; ++kk) {
            bf16x8 a = *(const bf16x8*)(sQ + (w * 16 + c) * 136 + kk * 32 + quad * 8);
            #pragma unroll
            for (int nt = 0; nt < 8; ++nt) {
                bf16x8 bb = *(const bf16x8*)(sVT + (nt * 16 + c) * 72 + kk * 32 + quad * 8);
                o[nt] = mfma16(a, bb, o[nt]);
            }
        }
        // ctx_h -> sQ (own rows; P consumed)
        #pragma unroll
        for (int nt = 0; nt < 8; ++nt)
            #pragma unroll
            for (int rr = 0; rr < 4; ++rr)
                sQ[(w * 16 + quad * 4 + rr) * 136 + nt * 16 + c] = f2bs(o[nt][rr]);
        // ---- out-proj partial: x += ctx_h @ Wo[:, h*128:+128]^T ----
        #pragma unroll
        for (int kk = 0; kk < 4; ++kk) {
            bf16x8 a = *(const bf16x8*)(sQ + (w * 16 + c) * 136 + kk * 32 + quad * 8);
            #pragma unroll
            for (int nt = 0; nt < 32; ++nt) {
                bf16x8 bb = *(const bf16x8*)(Wo + (size_t)(nt * 16 + c) * kD + h * 128 + kk * 32 + quad * 8);
                xacc[nt] = mfma16(a, bb, xacc[nt]);
            }
        }
    }

    // ---- epilogue: x = z_dc + att_out + bo; LayerNorm; store ----
    float sum[4] = {0, 0, 0, 0}, ssq[4] = {0, 0, 0, 0};
    #pragma unroll
    for (int nt = 0; nt < 32; ++nt)
        #pragma unroll
        for (int rr = 0; rr < 4; ++rr) {
            int trow = w * 16 + quad * 4 + rr;
            int col = nt * 16 + c;
            float zd = bs2f(zs[(size_t)trow * kD + col]) - 0.05f * (bs2f(sMean[col]) - bs2f(sZi[col]));
            float x = xacc[nt][rr] + bs2f(bo[col]) + zd;
            xacc[nt][rr] = x;
            sum[rr] += x; ssq[rr] += x * x;
        }
    float mu[4], rstd[4];
    #pragma unroll
    for (int rr = 0; rr < 4; ++rr) {
        float s = sum[rr], q = ssq[rr];
        for (int m = 1; m < 16; m <<= 1) { s += __shfl_xor(s, m, 64); q += __shfl_xor(q, m, 64); }
        float mm = s / (float)kD;
        float var = q / (float)kD - mm * mm;   // biased, eps 1e-5
        mu[rr] = mm;
        rstd[rr] = rsqrtf(var + 1e-5f);
    }
    #pragma unroll
    for (int nt = 0; nt < 32; ++nt)
        #pragma unroll
        for (int rr = 0; rr < 4; ++rr) {
            int trow = w * 16 + quad * 4 + rr;
            int col = nt * 16 + c;
            float v = (xacc[nt][rr] - mu[rr]) * rstd[rr] * bs2f(gm[col]) + bs2f(bt[col]);
            v = (v != v) ? 0.f : v;
            size_t idx = ((size_t)b * kT + trow) * kD + col;
            if (f32out) ((float*)outp)[idx] = v;
            else        ((s16*)outp)[idx] = f2bs(v);
        }
}

extern "C" void kernel_launch(void* const* d_in, const int* in_sizes, int n_in,
                              void* d_out, int out_size, void* d_ws, size_t ws_size,
                              hipStream_t stream) {
    (void)in_sizes; (void)n_in; (void)out_size;
    const size_t kStageElems = (size_t)kB * kT * kD;
    const size_t kNeed = 16 + (size_t)kTotalConv * 2 + kStageElems * 2;   // ~70.9 MB

    const s16* p[NSEG];
    s16* stage;
    void* outp = d_out;
    const int* flag = nullptr;
    int mode = 0;

    if (ws_size >= kNeed) {
        int* flg = (int*)d_ws;
        s16* conv = (s16*)((char*)d_ws + 16);
        stage = (s16*)((char*)d_ws + 16 + (size_t)kTotalConv * 2);
        detect_kernel<<<dim3(1), dim3(64), 0, stream>>>((const unsigned*)d_in[1], flg);
        ConvArgs ca;
        for (int i = 0; i < NSEG; ++i) ca.src[i] = d_in[i];
        convert_kernel<<<dim3(512), dim3(256), 0, stream>>>(ca, conv, flg);
        for (int i = 0; i < NSEG; ++i) p[i] = conv + kOff[i];
        flag = flg;
        mode = 1;
    } else {
        for (int i = 0; i < NSEG; ++i) p[i] = (const s16*)d_in[i];
        stage = (s16*)d_out;   // in-place staging (bf16 assumed)
    }

    ode_kernel<<<dim3(64), dim3(1024), 0, stream>>>(
        p[0], p[1], p[2], p[3], p[4], p[5], p[6], p[7], stage);
    attn_kernel<<<dim3(kB), dim3(256), 0, stream>>>(
        p[0], p[8], p[9], p[10], p[11], p[12], p[13], stage, outp, flag, mode);
}